// Round 1
// baseline (545.808 us; speedup 1.0000x reference)
//
#include <hip/hip_runtime.h>

typedef unsigned short u16;
typedef unsigned int u32;
typedef __bf16 bf16x8 __attribute__((ext_vector_type(8)));
typedef float f32x4 __attribute__((ext_vector_type(4)));

// ---------- helpers ----------
__device__ __forceinline__ u16 f2bf(float f) {
    u32 u = __builtin_bit_cast(u32, f);
    u32 r = u + 0x7FFFu + ((u >> 16) & 1u);   // round-to-nearest-even
    return (u16)(r >> 16);
}
__device__ __forceinline__ float bf2f(u16 h) {
    u32 u = ((u32)h) << 16;
    return __builtin_bit_cast(float, u);
}

// ---------- f32 -> bf16 conversion (vectorized) ----------
__global__ __launch_bounds__(256) void cvt_kernel(const float* __restrict__ in,
                                                  u16* __restrict__ out, int n4) {
    int i = blockIdx.x * 256 + threadIdx.x;
    if (i >= n4) return;
    float4 f = reinterpret_cast<const float4*>(in)[i];
    u32 lo = (u32)f2bf(f.x) | ((u32)f2bf(f.y) << 16);
    u32 hi = (u32)f2bf(f.z) | ((u32)f2bf(f.w) << 16);
    reinterpret_cast<uint2*>(out)[i] = make_uint2(lo, hi);
}

// ---------- GEMM: C[M,N] = A[M,K] @ B[N,K]^T, bf16 inputs, f32 or bf16 out ----------
// 128x128 block tile, BK=32, 256 threads = 4 waves (2x2), each wave 64x64 via 4x4 mfma tiles.
__global__ __launch_bounds__(256) void gemm_bt(const u16* __restrict__ A,
                                               const u16* __restrict__ Bw,
                                               float* __restrict__ Cf,
                                               u16* __restrict__ Cb,
                                               int M, int N, int K, int out_f32) {
    constexpr int LD = 40;   // 32 + 8 pad: 2-way bank aliasing only (free)
    __shared__ __align__(16) u16 As[128 * LD];
    __shared__ __align__(16) u16 Bs[128 * LD];
    const int tid = threadIdx.x;
    const int wave = tid >> 6, lane = tid & 63, quad = lane >> 4, l15 = lane & 15;
    const int wm = wave >> 1, wn = wave & 1;
    const int m0 = blockIdx.x * 128, n0 = blockIdx.y * 128;
    f32x4 acc[4][4];
#pragma unroll
    for (int a = 0; a < 4; a++)
#pragma unroll
        for (int b = 0; b < 4; b++) acc[a][b] = (f32x4){0.f, 0.f, 0.f, 0.f};
    const int sub = tid & 3, row = tid >> 2;   // 4 k-chunks of 8, 64 rows/pass
    for (int kk = 0; kk < K; kk += 32) {
        __syncthreads();
#pragma unroll
        for (int p = 0; p < 2; p++) {
            int r = row + p * 64;
            uint4 da = *reinterpret_cast<const uint4*>(A + (size_t)(m0 + r) * K + kk + sub * 8);
            uint4 db = *reinterpret_cast<const uint4*>(Bw + (size_t)(n0 + r) * K + kk + sub * 8);
            *reinterpret_cast<uint4*>(&As[r * LD + sub * 8]) = da;
            *reinterpret_cast<uint4*>(&Bs[r * LD + sub * 8]) = db;
        }
        __syncthreads();
        bf16x8 af[4], bfr[4];
#pragma unroll
        for (int t = 0; t < 4; t++) {
            af[t]  = *reinterpret_cast<const bf16x8*>(&As[(wm * 64 + t * 16 + l15) * LD + quad * 8]);
            bfr[t] = *reinterpret_cast<const bf16x8*>(&Bs[(wn * 64 + t * 16 + l15) * LD + quad * 8]);
        }
#pragma unroll
        for (int tm = 0; tm < 4; tm++)
#pragma unroll
            for (int tn = 0; tn < 4; tn++)
                acc[tm][tn] = __builtin_amdgcn_mfma_f32_16x16x32_bf16(af[tm], bfr[tn], acc[tm][tn], 0, 0, 0);
    }
    // epilogue: C/D layout col=l15, row=quad*4+i
#pragma unroll
    for (int tm = 0; tm < 4; tm++) {
        const int r0 = m0 + wm * 64 + tm * 16 + quad * 4;
#pragma unroll
        for (int tn = 0; tn < 4; tn++) {
            const int c = n0 + wn * 64 + tn * 16 + l15;
#pragma unroll
            for (int i = 0; i < 4; i++) {
                size_t off = (size_t)(r0 + i) * N + c;
                if (out_f32) Cf[off] = acc[tm][tn][i];
                else         Cb[off] = f2bf(acc[tm][tn][i]);
            }
        }
    }
}

// ---------- RoPE + scatter qkv[4096][3072] -> q[b][h][t][64], k/v[b][g][t][64] ----------
// one thread per (row, group, slot, half-dim); q gets pre-scaled by 1/sqrt(64)=0.125
__global__ __launch_bounds__(256) void rope_scatter(const u16* __restrict__ qkv,
                                                    const float* __restrict__ cosb,
                                                    const float* __restrict__ sinb,
                                                    u16* __restrict__ Qo,
                                                    u16* __restrict__ Ko,
                                                    u16* __restrict__ Vo) {
    int idx = blockIdx.x * 256 + threadIdx.x;   // 4096*48*32 total
    int dh = idx & 31;
    int rest = idx >> 5;
    int gs = rest % 48;        // g*6 + slot
    int r = rest / 48;         // 0..4095 (= b*2048 + t)
    int g = gs / 6, slot = gs % 6;
    int t = r & 2047, b = r >> 11;
    const u16* src = qkv + (size_t)r * 3072 + gs * 64;
    float x1 = bf2f(src[dh]), x2 = bf2f(src[dh + 32]);
    u16* dst;
    float o1, o2;
    if (slot < 4) {
        float c = cosb[t * 32 + dh], s = sinb[t * 32 + dh];
        o1 = (x1 * c - x2 * s) * 0.125f;
        o2 = (x2 * c + x1 * s) * 0.125f;
        int hh = g * 4 + slot;
        dst = Qo + (((size_t)(b * 32 + hh)) * 2048 + t) * 64;
    } else if (slot == 4) {
        float c = cosb[t * 32 + dh], s = sinb[t * 32 + dh];
        o1 = x1 * c - x2 * s;
        o2 = x2 * c + x1 * s;
        dst = Ko + (((size_t)(b * 8 + g)) * 2048 + t) * 64;
    } else {
        o1 = x1; o2 = x2;
        dst = Vo + (((size_t)(b * 8 + g)) * 2048 + t) * 64;
    }
    dst[dh] = f2bf(o1);
    dst[dh + 32] = f2bf(o2);
}

// ---------- flash attention: BQ=64, BK=64, 4 waves (16 q-rows each), online softmax ----------
__global__ __launch_bounds__(256) void attn(const u16* __restrict__ Q,
                                            const u16* __restrict__ Kg,
                                            const u16* __restrict__ V,
                                            u16* __restrict__ O) {
    constexpr int LD = 72;   // 64 + 8 pad
    __shared__ __align__(16) u16 Qs[64 * LD];
    __shared__ __align__(16) u16 Ks[64 * LD];
    __shared__ __align__(16) u16 Vts[64 * LD];    // transposed: [d][key]
    __shared__ __align__(16) u16 Ps[4][16 * LD];  // per-wave P tile [q][key]
    const int tid = threadIdx.x, wave = tid >> 6, lane = tid & 63;
    const int quad = lane >> 4, l15 = lane & 15;
    const int q0 = blockIdx.x * 64;
    const int h = blockIdx.y, b = blockIdx.z, g = h >> 2;
    const u16* qb = Q + (((size_t)(b * 32 + h)) * 2048 + q0) * 64;
    const u16* kb = Kg + ((size_t)(b * 8 + g)) * 2048 * 64;
    const u16* vb = V + ((size_t)(b * 8 + g)) * 2048 * 64;
    {
        const int sub = tid & 7, r0 = tid >> 3;
#pragma unroll
        for (int p = 0; p < 2; p++) {
            int r = r0 + p * 32;
            uint4 d = *reinterpret_cast<const uint4*>(qb + (size_t)r * 64 + sub * 8);
            *reinterpret_cast<uint4*>(&Qs[r * LD + sub * 8]) = d;
        }
    }
    __syncthreads();
    bf16x8 aq0 = *reinterpret_cast<const bf16x8*>(&Qs[(wave * 16 + l15) * LD + quad * 8]);
    bf16x8 aq1 = *reinterpret_cast<const bf16x8*>(&Qs[(wave * 16 + l15) * LD + 32 + quad * 8]);
    f32x4 Oc[4];
#pragma unroll
    for (int t = 0; t < 4; t++) Oc[t] = (f32x4){0.f, 0.f, 0.f, 0.f};
    float mrow[4] = {-1e30f, -1e30f, -1e30f, -1e30f};
    float lrow[4] = {0.f, 0.f, 0.f, 0.f};
    for (int kk = 0; kk < 2048; kk += 64) {
        __syncthreads();
        {
            const int sub = tid & 7, r0 = tid >> 3;
#pragma unroll
            for (int p = 0; p < 2; p++) {
                int r = r0 + p * 32;
                uint4 d = *reinterpret_cast<const uint4*>(kb + (size_t)(kk + r) * 64 + sub * 8);
                *reinterpret_cast<uint4*>(&Ks[r * LD + sub * 8]) = d;
            }
#pragma unroll
            for (int j = 0; j < 16; j++) {
                int idx = tid + 256 * j;
                int r = idx >> 6, d = idx & 63;
                Vts[d * LD + r] = vb[(size_t)(kk + r) * 64 + d];
            }
        }
        __syncthreads();
        // S = (Q*scale) @ K^T ; wave computes 16q x 64k
        f32x4 S[4];
#pragma unroll
        for (int tn = 0; tn < 4; tn++) {
            bf16x8 bk0 = *reinterpret_cast<const bf16x8*>(&Ks[(tn * 16 + l15) * LD + quad * 8]);
            bf16x8 bk1 = *reinterpret_cast<const bf16x8*>(&Ks[(tn * 16 + l15) * LD + 32 + quad * 8]);
            f32x4 z = (f32x4){0.f, 0.f, 0.f, 0.f};
            z = __builtin_amdgcn_mfma_f32_16x16x32_bf16(aq0, bk0, z, 0, 0, 0);
            z = __builtin_amdgcn_mfma_f32_16x16x32_bf16(aq1, bk1, z, 0, 0, 0);
            S[tn] = z;
        }
        // online softmax: row r = quad*4+i lives in this quad's 16 lanes x 4 tn regs
        float mloc[4], psum[4], alpha[4];
#pragma unroll
        for (int i = 0; i < 4; i++) {
            float mm = fmaxf(fmaxf(S[0][i], S[1][i]), fmaxf(S[2][i], S[3][i]));
#pragma unroll
            for (int off = 1; off < 16; off <<= 1) mm = fmaxf(mm, __shfl_xor(mm, off));
            float mn = fmaxf(mrow[i], mm);
            alpha[i] = __expf(mrow[i] - mn);
            mrow[i] = mn;
            psum[i] = 0.f;
        }
#pragma unroll
        for (int tn = 0; tn < 4; tn++) {
#pragma unroll
            for (int i = 0; i < 4; i++) {
                float p = __expf(S[tn][i] - mrow[i]);
                psum[i] += p;
                Ps[wave][(quad * 4 + i) * LD + tn * 16 + l15] = f2bf(p);
            }
        }
#pragma unroll
        for (int i = 0; i < 4; i++) {
            float ps = psum[i];
#pragma unroll
            for (int off = 1; off < 16; off <<= 1) ps += __shfl_xor(ps, off);
            lrow[i] = lrow[i] * alpha[i] + ps;
        }
#pragma unroll
        for (int t = 0; t < 4; t++) {
            f32x4 o = Oc[t];
            o[0] *= alpha[0]; o[1] *= alpha[1]; o[2] *= alpha[2]; o[3] *= alpha[3];
            Oc[t] = o;
        }
        __syncthreads();   // safe ordering of wave-private P LDS round-trip
        // O += P @ V : A = P[q=l15][key=ks*32+quad*8+j], B = Vt[d=tn*16+l15][key]
#pragma unroll
        for (int ks = 0; ks < 2; ks++) {
            bf16x8 ap = *reinterpret_cast<const bf16x8*>(&Ps[wave][l15 * LD + ks * 32 + quad * 8]);
#pragma unroll
            for (int t = 0; t < 4; t++) {
                bf16x8 bv = *reinterpret_cast<const bf16x8*>(&Vts[(t * 16 + l15) * LD + ks * 32 + quad * 8]);
                Oc[t] = __builtin_amdgcn_mfma_f32_16x16x32_bf16(ap, bv, Oc[t], 0, 0, 0);
            }
        }
    }
    // epilogue: out[b][t][h*64+d] bf16
#pragma unroll
    for (int i = 0; i < 4; i++) {
        float inv = 1.f / lrow[i];
        int t = q0 + wave * 16 + quad * 4 + i;
        u16* orow = O + ((size_t)(b * 2048 + t)) * 2048 + h * 64;
#pragma unroll
        for (int tn = 0; tn < 4; tn++) orow[tn * 16 + l15] = f2bf(Oc[tn][i] * inv);
    }
}

// ---------- launch ----------
extern "C" void kernel_launch(void* const* d_in, const int* in_sizes, int n_in,
                              void* d_out, int out_size, void* d_ws, size_t ws_size,
                              hipStream_t stream) {
    const float* x      = (const float*)d_in[0];
    const float* cosb   = (const float*)d_in[1];
    const float* sinb   = (const float*)d_in[2];
    const float* attn_w = (const float*)d_in[3];
    const float* proj_w = (const float*)d_in[4];
    float* out = (float*)d_out;

    // workspace layout (u16 elements); total ~75.5 MB
    u16* xb  = (u16*)d_ws;                     // 4096*2048 bf16 x
    u16* w1b = xb  + (size_t)4096 * 2048;      // 3072*2048 bf16 attn_w
    u16* w2b = w1b + (size_t)3072 * 2048;      // 2048*2048 bf16 proj_w
    u16* qkv = w2b + (size_t)2048 * 2048;      // 4096*3072 bf16 qkv
    u16* qo  = qkv + (size_t)4096 * 3072;      // 2*32*2048*64
    u16* ko  = qo  + (size_t)2 * 32 * 2048 * 64; // 2*8*2048*64
    u16* vo  = ko  + (size_t)2 * 8 * 2048 * 64;  // 2*8*2048*64
    u16* ao  = xb;   // attention output reuses x buffer (x consumed by GEMM1)

    cvt_kernel<<<8192, 256, 0, stream>>>(x, xb, 4096 * 2048 / 4);
    cvt_kernel<<<6144, 256, 0, stream>>>(attn_w, w1b, 3072 * 2048 / 4);
    cvt_kernel<<<4096, 256, 0, stream>>>(proj_w, w2b, 2048 * 2048 / 4);
    gemm_bt<<<dim3(32, 24), 256, 0, stream>>>(xb, w1b, nullptr, qkv, 4096, 3072, 2048, 0);
    rope_scatter<<<24576, 256, 0, stream>>>(qkv, cosb, sinb, qo, ko, vo);
    attn<<<dim3(32, 32, 2), 256, 0, stream>>>(qo, ko, vo, ao);
    gemm_bt<<<dim3(32, 16), 256, 0, stream>>>(ao, w2b, out, nullptr, 4096, 2048, 2048, 1);
}

// Round 2
// 399.087 us; speedup vs baseline: 1.3676x; 1.3676x over previous
//
#include <hip/hip_runtime.h>

typedef unsigned short u16;
typedef unsigned int u32;
typedef __bf16 bf16x8 __attribute__((ext_vector_type(8)));
typedef float f32x4 __attribute__((ext_vector_type(4)));
typedef float f32x16 __attribute__((ext_vector_type(16)));

// ---------- helpers ----------
__device__ __forceinline__ u16 f2bf(float f) {
    u32 u = __builtin_bit_cast(u32, f);
    u32 r = u + 0x7FFFu + ((u >> 16) & 1u);   // round-to-nearest-even
    return (u16)(r >> 16);
}
__device__ __forceinline__ float bf2f(u16 h) {
    u32 u = ((u32)h) << 16;
    return __builtin_bit_cast(float, u);
}

// ---------- f32 -> bf16 conversion (vectorized) ----------
__global__ __launch_bounds__(256) void cvt_kernel(const float* __restrict__ in,
                                                  u16* __restrict__ out, int n4) {
    int i = blockIdx.x * 256 + threadIdx.x;
    if (i >= n4) return;
    float4 f = reinterpret_cast<const float4*>(in)[i];
    u32 lo = (u32)f2bf(f.x) | ((u32)f2bf(f.y) << 16);
    u32 hi = (u32)f2bf(f.z) | ((u32)f2bf(f.w) << 16);
    reinterpret_cast<uint2*>(out)[i] = make_uint2(lo, hi);
}

// ---------- GEMM: C[M,N] = A[M,K] @ B[N,K]^T, bf16 inputs, f32 or bf16 out ----------
__global__ __launch_bounds__(256) void gemm_bt(const u16* __restrict__ A,
                                               const u16* __restrict__ Bw,
                                               float* __restrict__ Cf,
                                               u16* __restrict__ Cb,
                                               int M, int N, int K, int out_f32) {
    constexpr int LD = 40;
    __shared__ __align__(16) u16 As[128 * LD];
    __shared__ __align__(16) u16 Bs[128 * LD];
    const int tid = threadIdx.x;
    const int wave = tid >> 6, lane = tid & 63, quad = lane >> 4, l15 = lane & 15;
    const int wm = wave >> 1, wn = wave & 1;
    const int m0 = blockIdx.x * 128, n0 = blockIdx.y * 128;
    f32x4 acc[4][4];
#pragma unroll
    for (int a = 0; a < 4; a++)
#pragma unroll
        for (int b = 0; b < 4; b++) acc[a][b] = (f32x4){0.f, 0.f, 0.f, 0.f};
    const int sub = tid & 3, row = tid >> 2;
    for (int kk = 0; kk < K; kk += 32) {
        __syncthreads();
#pragma unroll
        for (int p = 0; p < 2; p++) {
            int r = row + p * 64;
            uint4 da = *reinterpret_cast<const uint4*>(A + (size_t)(m0 + r) * K + kk + sub * 8);
            uint4 db = *reinterpret_cast<const uint4*>(Bw + (size_t)(n0 + r) * K + kk + sub * 8);
            *reinterpret_cast<uint4*>(&As[r * LD + sub * 8]) = da;
            *reinterpret_cast<uint4*>(&Bs[r * LD + sub * 8]) = db;
        }
        __syncthreads();
        bf16x8 af[4], bfr[4];
#pragma unroll
        for (int t = 0; t < 4; t++) {
            af[t]  = *reinterpret_cast<const bf16x8*>(&As[(wm * 64 + t * 16 + l15) * LD + quad * 8]);
            bfr[t] = *reinterpret_cast<const bf16x8*>(&Bs[(wn * 64 + t * 16 + l15) * LD + quad * 8]);
        }
#pragma unroll
        for (int tm = 0; tm < 4; tm++)
#pragma unroll
            for (int tn = 0; tn < 4; tn++)
                acc[tm][tn] = __builtin_amdgcn_mfma_f32_16x16x32_bf16(af[tm], bfr[tn], acc[tm][tn], 0, 0, 0);
    }
#pragma unroll
    for (int tm = 0; tm < 4; tm++) {
        const int r0 = m0 + wm * 64 + tm * 16 + quad * 4;
#pragma unroll
        for (int tn = 0; tn < 4; tn++) {
            const int c = n0 + wn * 64 + tn * 16 + l15;
#pragma unroll
            for (int i = 0; i < 4; i++) {
                size_t off = (size_t)(r0 + i) * N + c;
                if (out_f32) Cf[off] = acc[tm][tn][i];
                else         Cb[off] = f2bf(acc[tm][tn][i]);
            }
        }
    }
}

// ---------- RoPE + scatter qkv[4096][3072] -> q[b][h][t][64], k/v[b][g][t][64] ----------
// q pre-scaled by (1/sqrt(64)) * log2(e) so attention softmax runs in base-2 domain
#define QSCALE 0.18033688011111793f
__global__ __launch_bounds__(256) void rope_scatter(const u16* __restrict__ qkv,
                                                    const float* __restrict__ cosb,
                                                    const float* __restrict__ sinb,
                                                    u16* __restrict__ Qo,
                                                    u16* __restrict__ Ko,
                                                    u16* __restrict__ Vo) {
    int idx = blockIdx.x * 256 + threadIdx.x;
    int dh = idx & 31;
    int rest = idx >> 5;
    int gs = rest % 48;
    int r = rest / 48;
    int g = gs / 6, slot = gs % 6;
    int t = r & 2047, b = r >> 11;
    const u16* src = qkv + (size_t)r * 3072 + gs * 64;
    float x1 = bf2f(src[dh]), x2 = bf2f(src[dh + 32]);
    u16* dst;
    float o1, o2;
    if (slot < 4) {
        float c = cosb[t * 32 + dh], s = sinb[t * 32 + dh];
        o1 = (x1 * c - x2 * s) * QSCALE;
        o2 = (x2 * c + x1 * s) * QSCALE;
        int hh = g * 4 + slot;
        dst = Qo + (((size_t)(b * 32 + hh)) * 2048 + t) * 64;
    } else if (slot == 4) {
        float c = cosb[t * 32 + dh], s = sinb[t * 32 + dh];
        o1 = x1 * c - x2 * s;
        o2 = x2 * c + x1 * s;
        dst = Ko + (((size_t)(b * 8 + g)) * 2048 + t) * 64;
    } else {
        o1 = x1; o2 = x2;
        dst = Vo + (((size_t)(b * 8 + g)) * 2048 + t) * 64;
    }
    dst[dh] = f2bf(o1);
    dst[dh + 32] = f2bf(o2);
}

// ---------- V transpose: [bg][t][64] -> [bg][64][t], 64x64 LDS tiles ----------
__global__ __launch_bounds__(256) void vtrans(const u16* __restrict__ Vi,
                                              u16* __restrict__ Vt) {
    constexpr int LD = 72;
    __shared__ __align__(16) u16 Vs[64 * LD];
    const int t0 = blockIdx.x * 64;
    const int bg = blockIdx.y;
    const int tid = threadIdx.x, r = tid >> 3, c = tid & 7;
    const u16* src = Vi + (size_t)bg * 2048 * 64;
    u16* dst = Vt + (size_t)bg * 64 * 2048;
#pragma unroll
    for (int p = 0; p < 2; p++) {
        uint4 d = *reinterpret_cast<const uint4*>(src + (size_t)(t0 + r + p * 32) * 64 + c * 8);
        *reinterpret_cast<uint4*>(&Vs[(r + p * 32) * LD + c * 8]) = d;
    }
    __syncthreads();
#pragma unroll
    for (int p = 0; p < 2; p++) {
        int d = r + p * 32;
        u16 tmp[8];
#pragma unroll
        for (int j = 0; j < 8; j++) tmp[j] = Vs[(c * 8 + j) * LD + d];
        *reinterpret_cast<uint4*>(dst + (size_t)d * 2048 + t0 + c * 8) =
            *reinterpret_cast<uint4*>(tmp);
    }
}

// ---------- flash attention v2: BQ=128 (4 waves x 32 q-cols), BK=64, 32x32x16 MFMA ----------
// S^T formulation: S^T[key][q] = K-frag x Q-frag; per-lane scalar softmax state (q = lane&31);
// O accumulated as O^T[d][q]; V pre-transposed globally; base-2 softmax.
__global__ __launch_bounds__(256, 4) void attn(const u16* __restrict__ Q,
                                               const u16* __restrict__ Kg,
                                               const u16* __restrict__ Vt,
                                               u16* __restrict__ O) {
    constexpr int LDK = 72;   // mult of 8 (b128 align)
    constexpr int LDP = 88;   // mult of 8; bank advance 12 -> 2-way only
    __shared__ __align__(16) u16 Ks[64 * LDK];
    __shared__ __align__(16) u16 Vts[64 * LDK];
    __shared__ __align__(16) u16 Ps[4 * 32 * LDP];   // per-wave P; also Q staging scratch
    const int tid = threadIdx.x, w = tid >> 6, lane = tid & 63;
    const int half = lane >> 5, l31 = lane & 31;
    const int q0 = blockIdx.x * 128;
    const int h = blockIdx.y, b = blockIdx.z, g = h >> 2;
    const u16* qb = Q + (((size_t)(b * 32 + h)) * 2048 + q0) * 64;
    const u16* kb = Kg + ((size_t)(b * 8 + g)) * 2048 * 64;
    const u16* vb = Vt + ((size_t)(b * 8 + g)) * 64 * 2048;

    // stage Q (128x64) into Ps scratch, read per-wave B-fragments, then release
    {
        const int r = tid >> 3, c = tid & 7;
#pragma unroll
        for (int p = 0; p < 4; p++) {
            uint4 d = *reinterpret_cast<const uint4*>(qb + (size_t)(r + p * 32) * 64 + c * 8);
            *reinterpret_cast<uint4*>(&Ps[(r + p * 32) * LDK + c * 8]) = d;
        }
    }
    __syncthreads();
    bf16x8 qf[4];
#pragma unroll
    for (int ks = 0; ks < 4; ks++)
        qf[ks] = *reinterpret_cast<const bf16x8*>(&Ps[(w * 32 + l31) * LDK + ks * 16 + half * 8]);
    __syncthreads();

    f32x16 Oa[2];
#pragma unroll
    for (int t = 0; t < 2; t++)
#pragma unroll
        for (int i = 0; i < 16; i++) Oa[t][i] = 0.f;
    float m = -1e30f, l = 0.f;
    u16* Pw = Ps + w * 32 * LDP;

    for (int kk = 0; kk < 2048; kk += 64) {
        __syncthreads();
        {
            const int r = tid >> 3, c = tid & 7;
#pragma unroll
            for (int p = 0; p < 2; p++) {
                uint4 dk = *reinterpret_cast<const uint4*>(kb + (size_t)(kk + r + p * 32) * 64 + c * 8);
                *reinterpret_cast<uint4*>(&Ks[(r + p * 32) * LDK + c * 8]) = dk;
                uint4 dv = *reinterpret_cast<const uint4*>(vb + (size_t)(r + p * 32) * 2048 + kk + c * 8);
                *reinterpret_cast<uint4*>(&Vts[(r + p * 32) * LDK + c * 8]) = dv;
            }
        }
        __syncthreads();
        // S^T[key 64][q 32]: A = K-frag [key][d], B = Q-frag [q][d]
        f32x16 S[2];
#pragma unroll
        for (int kt = 0; kt < 2; kt++) {
#pragma unroll
            for (int i = 0; i < 16; i++) S[kt][i] = 0.f;
#pragma unroll
            for (int ks = 0; ks < 4; ks++) {
                bf16x8 kf = *reinterpret_cast<const bf16x8*>(
                    &Ks[(kt * 32 + l31) * LDK + ks * 16 + half * 8]);
                S[kt] = __builtin_amdgcn_mfma_f32_32x32x16_bf16(kf, qf[ks], S[kt], 0, 0, 0);
            }
        }
        // online softmax, base-2; this lane owns column q = l31 (all 32 S vals same q)
        float mloc = S[0][0];
#pragma unroll
        for (int i = 1; i < 16; i++) mloc = fmaxf(mloc, S[0][i]);
#pragma unroll
        for (int i = 0; i < 16; i++) mloc = fmaxf(mloc, S[1][i]);
        mloc = fmaxf(mloc, __shfl_xor(mloc, 32));
        float mnew = fmaxf(m, mloc);
        float alpha = __builtin_amdgcn_exp2f(m - mnew);
        float ps = 0.f;
#pragma unroll
        for (int kt = 0; kt < 2; kt++)
#pragma unroll
            for (int i = 0; i < 16; i++) {
                float p = __builtin_amdgcn_exp2f(S[kt][i] - mnew);
                ps += p;
                S[kt][i] = p;
            }
        // write P[q][key] packed: reg&3 = consecutive keys -> b64 stores
#pragma unroll
        for (int kt = 0; kt < 2; kt++)
#pragma unroll
            for (int gr = 0; gr < 4; gr++) {
                u16 tmp[4];
#pragma unroll
                for (int i = 0; i < 4; i++) tmp[i] = f2bf(S[kt][gr * 4 + i]);
                *reinterpret_cast<uint2*>(&Pw[l31 * LDP + kt * 32 + gr * 8 + half * 4]) =
                    *reinterpret_cast<uint2*>(tmp);
            }
        ps += __shfl_xor(ps, 32);
        l = l * alpha + ps;
        m = mnew;
#pragma unroll
        for (int t = 0; t < 2; t++)
#pragma unroll
            for (int i = 0; i < 16; i++) Oa[t][i] *= alpha;
        // O^T[d][q] += Vt-frag [d][key] x P-frag [q][key]
#pragma unroll
        for (int ks2 = 0; ks2 < 4; ks2++) {
            bf16x8 pf = *reinterpret_cast<const bf16x8*>(&Pw[l31 * LDP + ks2 * 16 + half * 8]);
#pragma unroll
            for (int dt = 0; dt < 2; dt++) {
                bf16x8 vf = *reinterpret_cast<const bf16x8*>(
                    &Vts[(dt * 32 + l31) * LDK + ks2 * 16 + half * 8]);
                Oa[dt] = __builtin_amdgcn_mfma_f32_32x32x16_bf16(vf, pf, Oa[dt], 0, 0, 0);
            }
        }
    }
    // epilogue: O^T C-layout row d = dt*32 + 8*gr + 4*half + i, col q = l31
    float linv = 1.f / l;
    const int t = q0 + w * 32 + l31;
    u16* orow = O + ((size_t)(b * 2048 + t)) * 2048 + h * 64;
#pragma unroll
    for (int dt = 0; dt < 2; dt++)
#pragma unroll
        for (int gr = 0; gr < 4; gr++) {
            u16 tmp[4];
#pragma unroll
            for (int i = 0; i < 4; i++) tmp[i] = f2bf(Oa[dt][gr * 4 + i] * linv);
            *reinterpret_cast<uint2*>(orow + dt * 32 + 8 * gr + 4 * half) =
                *reinterpret_cast<uint2*>(tmp);
        }
}

// ---------- launch ----------
extern "C" void kernel_launch(void* const* d_in, const int* in_sizes, int n_in,
                              void* d_out, int out_size, void* d_ws, size_t ws_size,
                              hipStream_t stream) {
    const float* x      = (const float*)d_in[0];
    const float* cosb   = (const float*)d_in[1];
    const float* sinb   = (const float*)d_in[2];
    const float* attn_w = (const float*)d_in[3];
    const float* proj_w = (const float*)d_in[4];
    float* out = (float*)d_out;

    u16* xb  = (u16*)d_ws;                       // 4096*2048
    u16* w1b = xb  + (size_t)4096 * 2048;        // 3072*2048
    u16* w2b = w1b + (size_t)3072 * 2048;        // 2048*2048
    u16* qkv = w2b + (size_t)2048 * 2048;        // 4096*3072
    u16* qo  = qkv + (size_t)4096 * 3072;        // 2*32*2048*64
    u16* ko  = qo  + (size_t)2 * 32 * 2048 * 64; // 2*8*2048*64
    u16* vo  = ko  + (size_t)2 * 8 * 2048 * 64;  // 2*8*2048*64
    u16* vt  = w1b;  // V^T reuses attn_w-bf16 buffer (consumed by GEMM1)
    u16* ao  = xb;   // attention output reuses x buffer (consumed by GEMM1)

    cvt_kernel<<<8192, 256, 0, stream>>>(x, xb, 4096 * 2048 / 4);
    cvt_kernel<<<6144, 256, 0, stream>>>(attn_w, w1b, 3072 * 2048 / 4);
    cvt_kernel<<<4096, 256, 0, stream>>>(proj_w, w2b, 2048 * 2048 / 4);
    gemm_bt<<<dim3(32, 24), 256, 0, stream>>>(xb, w1b, nullptr, qkv, 4096, 3072, 2048, 0);
    rope_scatter<<<24576, 256, 0, stream>>>(qkv, cosb, sinb, qo, ko, vo);
    vtrans<<<dim3(32, 16), 256, 0, stream>>>(vo, vt);
    attn<<<dim3(16, 32, 2), 256, 0, stream>>>(qo, ko, vt, ao);
    gemm_bt<<<dim3(32, 16), 256, 0, stream>>>(ao, w2b, out, nullptr, 4096, 2048, 2048, 1);
}

// Round 3
// 377.471 us; speedup vs baseline: 1.4460x; 1.0573x over previous
//
#include <hip/hip_runtime.h>

typedef unsigned short u16;
typedef unsigned int u32;
typedef __bf16 bf16x8 __attribute__((ext_vector_type(8)));
typedef float f32x4 __attribute__((ext_vector_type(4)));
typedef float f32x16 __attribute__((ext_vector_type(16)));

// ---------- helpers ----------
__device__ __forceinline__ u16 f2bf(float f) {
    u32 u = __builtin_bit_cast(u32, f);
    u32 r = u + 0x7FFFu + ((u >> 16) & 1u);   // round-to-nearest-even
    return (u16)(r >> 16);
}
__device__ __forceinline__ float bf2f(u16 h) {
    u32 u = ((u32)h) << 16;
    return __builtin_bit_cast(float, u);
}
// pack two f32 -> bf16x2 (round-half-up: 1 add + share perm); v0 low, v1 high
__device__ __forceinline__ u32 pack_bf16(float v0, float v1) {
    u32 a = __builtin_bit_cast(u32, v0) + 0x8000u;
    u32 b = __builtin_bit_cast(u32, v1) + 0x8000u;
    return __builtin_amdgcn_perm(b, a, 0x07060302u);  // {b.hi16, a.hi16}
}
// async global->LDS, 16B per lane; lptr must be wave-uniform (dest = lptr + lane*16B)
__device__ __forceinline__ void gload16(const u16* g, u16* l) {
    __builtin_amdgcn_global_load_lds(
        (const __attribute__((address_space(1))) u32*)g,
        (__attribute__((address_space(3))) u32*)l, 16, 0, 0);
}

// ---------- f32 -> bf16 conversion (vectorized) ----------
__global__ __launch_bounds__(256) void cvt_kernel(const float* __restrict__ in,
                                                  u16* __restrict__ out, int n4) {
    int i = blockIdx.x * 256 + threadIdx.x;
    if (i >= n4) return;
    float4 f = reinterpret_cast<const float4*>(in)[i];
    u32 lo = (u32)f2bf(f.x) | ((u32)f2bf(f.y) << 16);
    u32 hi = (u32)f2bf(f.z) | ((u32)f2bf(f.w) << 16);
    reinterpret_cast<uint2*>(out)[i] = make_uint2(lo, hi);
}

// ---------- GEMM (m97 structure): C[M,N] = A[M,K] @ B[N,K]^T ----------
// 128x128 tile, BK=32, 4 waves 2x2, global_load_lds width-16 staging, unpadded LDS.
__global__ __launch_bounds__(256) void gemm_bt(const u16* __restrict__ A,
                                               const u16* __restrict__ Bw,
                                               float* __restrict__ Cf,
                                               u16* __restrict__ Cb,
                                               int M, int N, int K, int out_f32) {
    __shared__ __align__(16) u16 As[128 * 32];
    __shared__ __align__(16) u16 Bs[128 * 32];
    const int tid = threadIdx.x;
    const int wave = tid >> 6, lane = tid & 63, quad = lane >> 4, l15 = lane & 15;
    const int wm = wave >> 1, wn = wave & 1;
    const int m0 = blockIdx.x * 128, n0 = blockIdx.y * 128;
    const int lrow = lane >> 2, lcol = (lane & 3) * 8;   // lane*16B = lrow*64B + lcol*2B
    f32x4 acc[4][4];
#pragma unroll
    for (int a = 0; a < 4; a++)
#pragma unroll
        for (int b = 0; b < 4; b++) acc[a][b] = (f32x4){0.f, 0.f, 0.f, 0.f};
    for (int kk = 0; kk < K; kk += 32) {
        __syncthreads();
#pragma unroll
        for (int c = 0; c < 2; c++) {
            const int rA = wave * 32 + c * 16;           // wave-uniform row base
            gload16(A  + (size_t)(m0 + rA + lrow) * K + kk + lcol, &As[rA * 32]);
            gload16(Bw + (size_t)(n0 + rA + lrow) * K + kk + lcol, &Bs[rA * 32]);
        }
        __syncthreads();
        bf16x8 af[4], bfr[4];
#pragma unroll
        for (int t = 0; t < 4; t++) {
            af[t]  = *reinterpret_cast<const bf16x8*>(&As[(wm * 64 + t * 16 + l15) * 32 + quad * 8]);
            bfr[t] = *reinterpret_cast<const bf16x8*>(&Bs[(wn * 64 + t * 16 + l15) * 32 + quad * 8]);
        }
#pragma unroll
        for (int tm = 0; tm < 4; tm++)
#pragma unroll
            for (int tn = 0; tn < 4; tn++)
                acc[tm][tn] = __builtin_amdgcn_mfma_f32_16x16x32_bf16(af[tm], bfr[tn], acc[tm][tn], 0, 0, 0);
    }
#pragma unroll
    for (int tm = 0; tm < 4; tm++) {
        const int r0 = m0 + wm * 64 + tm * 16 + quad * 4;
#pragma unroll
        for (int tn = 0; tn < 4; tn++) {
            const int c = n0 + wn * 64 + tn * 16 + l15;
#pragma unroll
            for (int i = 0; i < 4; i++) {
                size_t off = (size_t)(r0 + i) * N + c;
                if (out_f32) Cf[off] = acc[tm][tn][i];
                else         Cb[off] = f2bf(acc[tm][tn][i]);
            }
        }
    }
}

// ---------- RoPE + scatter, x8 vectorized ----------
// q pre-scaled by (1/sqrt(64)) * log2(e) so attention softmax runs in base-2 domain
#define QSCALE 0.18033688011111793f
__global__ __launch_bounds__(256) void rope_scatter(const u16* __restrict__ qkv,
                                                    const float* __restrict__ cosb,
                                                    const float* __restrict__ sinb,
                                                    u16* __restrict__ Qo,
                                                    u16* __restrict__ Ko,
                                                    u16* __restrict__ Vo) {
    int idx = blockIdx.x * 256 + threadIdx.x;   // ((r*48 + gs)*4 + c), total 4096*48*4
    int c = idx & 3;
    int rest = idx >> 2;
    int gs = rest % 48;
    int r = rest / 48;
    int g = gs / 6, slot = gs % 6;
    int t = r & 2047, b = r >> 11;
    const u16* src = qkv + (size_t)r * 3072 + gs * 64 + c * 8;
    u16 lo[8], hi[8], olo[8], ohi[8];
    *reinterpret_cast<uint4*>(lo) = *reinterpret_cast<const uint4*>(src);
    *reinterpret_cast<uint4*>(hi) = *reinterpret_cast<const uint4*>(src + 32);
    if (slot < 5) {
        float cc[8], ss[8];
        *reinterpret_cast<float4*>(&cc[0]) = *reinterpret_cast<const float4*>(cosb + t * 32 + c * 8);
        *reinterpret_cast<float4*>(&cc[4]) = *reinterpret_cast<const float4*>(cosb + t * 32 + c * 8 + 4);
        *reinterpret_cast<float4*>(&ss[0]) = *reinterpret_cast<const float4*>(sinb + t * 32 + c * 8);
        *reinterpret_cast<float4*>(&ss[4]) = *reinterpret_cast<const float4*>(sinb + t * 32 + c * 8 + 4);
        const float sc = (slot < 4) ? QSCALE : 1.0f;
#pragma unroll
        for (int j = 0; j < 8; j++) {
            float x1 = bf2f(lo[j]), x2 = bf2f(hi[j]);
            olo[j] = f2bf((x1 * cc[j] - x2 * ss[j]) * sc);
            ohi[j] = f2bf((x2 * cc[j] + x1 * ss[j]) * sc);
        }
    } else {
#pragma unroll
        for (int j = 0; j < 8; j++) { olo[j] = lo[j]; ohi[j] = hi[j]; }
    }
    u16* dst;
    if (slot < 4)      dst = Qo + (((size_t)(b * 32 + g * 4 + slot)) * 2048 + t) * 64 + c * 8;
    else if (slot == 4) dst = Ko + (((size_t)(b * 8 + g)) * 2048 + t) * 64 + c * 8;
    else                dst = Vo + (((size_t)(b * 8 + g)) * 2048 + t) * 64 + c * 8;
    *reinterpret_cast<uint4*>(dst)      = *reinterpret_cast<uint4*>(olo);
    *reinterpret_cast<uint4*>(dst + 32) = *reinterpret_cast<uint4*>(ohi);
}

// ---------- V transpose: [bg][t][64] -> [bg][64][t] ----------
__global__ __launch_bounds__(256) void vtrans(const u16* __restrict__ Vi,
                                              u16* __restrict__ Vt) {
    constexpr int LD = 72;
    __shared__ __align__(16) u16 Vs[64 * LD];
    const int t0 = blockIdx.x * 64;
    const int bg = blockIdx.y;
    const int tid = threadIdx.x, r = tid >> 3, c = tid & 7;
    const u16* src = Vi + (size_t)bg * 2048 * 64;
    u16* dst = Vt + (size_t)bg * 64 * 2048;
#pragma unroll
    for (int p = 0; p < 2; p++) {
        uint4 d = *reinterpret_cast<const uint4*>(src + (size_t)(t0 + r + p * 32) * 64 + c * 8);
        *reinterpret_cast<uint4*>(&Vs[(r + p * 32) * LD + c * 8]) = d;
    }
    __syncthreads();
#pragma unroll
    for (int p = 0; p < 2; p++) {
        int d = r + p * 32;
        u16 tmp[8];
#pragma unroll
        for (int j = 0; j < 8; j++) tmp[j] = Vs[(c * 8 + j) * LD + d];
        *reinterpret_cast<uint4*>(dst + (size_t)d * 2048 + t0 + c * 8) =
            *reinterpret_cast<uint4*>(tmp);
    }
}

// ---------- flash attention: BQ=128 (4 waves x 32 q-cols), BK=64, 32x32x16 MFMA ----------
__global__ __launch_bounds__(256, 4) void attn(const u16* __restrict__ Q,
                                               const u16* __restrict__ Kg,
                                               const u16* __restrict__ Vt,
                                               u16* __restrict__ O) {
    constexpr int LDK = 72;
    constexpr int LDP = 88;
    __shared__ __align__(16) u16 Ks[64 * LDK];
    __shared__ __align__(16) u16 Vts[64 * LDK];
    __shared__ __align__(16) u16 Ps[4 * 32 * LDP];
    const int tid = threadIdx.x, w = tid >> 6, lane = tid & 63;
    const int half = lane >> 5, l31 = lane & 31;
    const int q0 = blockIdx.x * 128;
    const int h = blockIdx.y, b = blockIdx.z, g = h >> 2;
    const u16* qb = Q + (((size_t)(b * 32 + h)) * 2048 + q0) * 64;
    const u16* kb = Kg + ((size_t)(b * 8 + g)) * 2048 * 64;
    const u16* vb = Vt + ((size_t)(b * 8 + g)) * 64 * 2048;

    {
        const int r = tid >> 3, c = tid & 7;
#pragma unroll
        for (int p = 0; p < 4; p++) {
            uint4 d = *reinterpret_cast<const uint4*>(qb + (size_t)(r + p * 32) * 64 + c * 8);
            *reinterpret_cast<uint4*>(&Ps[(r + p * 32) * LDK + c * 8]) = d;
        }
    }
    __syncthreads();
    bf16x8 qf[4];
#pragma unroll
    for (int ks = 0; ks < 4; ks++)
        qf[ks] = *reinterpret_cast<const bf16x8*>(&Ps[(w * 32 + l31) * LDK + ks * 16 + half * 8]);
    __syncthreads();

    f32x16 Oa[2];
#pragma unroll
    for (int t = 0; t < 2; t++)
#pragma unroll
        for (int i = 0; i < 16; i++) Oa[t][i] = 0.f;
    float m = -1e30f, l = 0.f;
    u16* Pw = Ps + w * 32 * LDP;

    for (int kk = 0; kk < 2048; kk += 64) {
        __syncthreads();
        {
            const int r = tid >> 3, c = tid & 7;
#pragma unroll
            for (int p = 0; p < 2; p++) {
                uint4 dk = *reinterpret_cast<const uint4*>(kb + (size_t)(kk + r + p * 32) * 64 + c * 8);
                *reinterpret_cast<uint4*>(&Ks[(r + p * 32) * LDK + c * 8]) = dk;
                uint4 dv = *reinterpret_cast<const uint4*>(vb + (size_t)(r + p * 32) * 2048 + kk + c * 8);
                *reinterpret_cast<uint4*>(&Vts[(r + p * 32) * LDK + c * 8]) = dv;
            }
        }
        __syncthreads();
        f32x16 S[2];
#pragma unroll
        for (int kt = 0; kt < 2; kt++) {
#pragma unroll
            for (int i = 0; i < 16; i++) S[kt][i] = 0.f;
#pragma unroll
            for (int ks = 0; ks < 4; ks++) {
                bf16x8 kf = *reinterpret_cast<const bf16x8*>(
                    &Ks[(kt * 32 + l31) * LDK + ks * 16 + half * 8]);
                S[kt] = __builtin_amdgcn_mfma_f32_32x32x16_bf16(kf, qf[ks], S[kt], 0, 0, 0);
            }
        }
        float mloc = S[0][0];
#pragma unroll
        for (int i = 1; i < 16; i++) mloc = fmaxf(mloc, S[0][i]);
#pragma unroll
        for (int i = 0; i < 16; i++) mloc = fmaxf(mloc, S[1][i]);
        mloc = fmaxf(mloc, __shfl_xor(mloc, 32));
        float mnew = fmaxf(m, mloc);
        float alpha = __builtin_amdgcn_exp2f(m - mnew);
        float ps = 0.f;
#pragma unroll
        for (int kt = 0; kt < 2; kt++)
#pragma unroll
            for (int i = 0; i < 16; i++) {
                float p = __builtin_amdgcn_exp2f(S[kt][i] - mnew);
                ps += p;
                S[kt][i] = p;
            }
        // packed P write: v_perm pairs, b64 stores
#pragma unroll
        for (int kt = 0; kt < 2; kt++)
#pragma unroll
            for (int gr = 0; gr < 4; gr++) {
                uint2 pk;
                pk.x = pack_bf16(S[kt][gr * 4 + 0], S[kt][gr * 4 + 1]);
                pk.y = pack_bf16(S[kt][gr * 4 + 2], S[kt][gr * 4 + 3]);
                *reinterpret_cast<uint2*>(&Pw[l31 * LDP + kt * 32 + gr * 8 + half * 4]) = pk;
            }
        ps += __shfl_xor(ps, 32);
        l = l * alpha + ps;
        m = mnew;
#pragma unroll
        for (int t = 0; t < 2; t++)
#pragma unroll
            for (int i = 0; i < 16; i++) Oa[t][i] *= alpha;
#pragma unroll
        for (int ks2 = 0; ks2 < 4; ks2++) {
            bf16x8 pf = *reinterpret_cast<const bf16x8*>(&Pw[l31 * LDP + ks2 * 16 + half * 8]);
#pragma unroll
            for (int dt = 0; dt < 2; dt++) {
                bf16x8 vf = *reinterpret_cast<const bf16x8*>(
                    &Vts[(dt * 32 + l31) * LDK + ks2 * 16 + half * 8]);
                Oa[dt] = __builtin_amdgcn_mfma_f32_32x32x16_bf16(vf, pf, Oa[dt], 0, 0, 0);
            }
        }
    }
    float linv = 1.f / l;
    const int t = q0 + w * 32 + l31;
    u16* orow = O + ((size_t)(b * 2048 + t)) * 2048 + h * 64;
#pragma unroll
    for (int dt = 0; dt < 2; dt++)
#pragma unroll
        for (int gr = 0; gr < 4; gr++) {
            u16 tmp[4];
#pragma unroll
            for (int i = 0; i < 4; i++) tmp[i] = f2bf(Oa[dt][gr * 4 + i] * linv);
            *reinterpret_cast<uint2*>(orow + dt * 32 + 8 * gr + 4 * half) =
                *reinterpret_cast<uint2*>(tmp);
        }
}

// ---------- launch ----------
extern "C" void kernel_launch(void* const* d_in, const int* in_sizes, int n_in,
                              void* d_out, int out_size, void* d_ws, size_t ws_size,
                              hipStream_t stream) {
    const float* x      = (const float*)d_in[0];
    const float* cosb   = (const float*)d_in[1];
    const float* sinb   = (const float*)d_in[2];
    const float* attn_w = (const float*)d_in[3];
    const float* proj_w = (const float*)d_in[4];
    float* out = (float*)d_out;

    u16* xb  = (u16*)d_ws;                       // 4096*2048
    u16* w1b = xb  + (size_t)4096 * 2048;        // 3072*2048
    u16* w2b = w1b + (size_t)3072 * 2048;        // 2048*2048
    u16* qkv = w2b + (size_t)2048 * 2048;        // 4096*3072
    u16* qo  = qkv + (size_t)4096 * 3072;        // 2*32*2048*64
    u16* ko  = qo  + (size_t)2 * 32 * 2048 * 64; // 2*8*2048*64
    u16* vo  = ko  + (size_t)2 * 8 * 2048 * 64;  // 2*8*2048*64
    u16* vt  = w1b;  // V^T reuses attn_w-bf16 buffer (consumed by GEMM1)
    u16* ao  = xb;   // attention output reuses x buffer (consumed by GEMM1)

    cvt_kernel<<<8192, 256, 0, stream>>>(x, xb, 4096 * 2048 / 4);
    cvt_kernel<<<6144, 256, 0, stream>>>(attn_w, w1b, 3072 * 2048 / 4);
    cvt_kernel<<<4096, 256, 0, stream>>>(proj_w, w2b, 2048 * 2048 / 4);
    gemm_bt<<<dim3(32, 24), 256, 0, stream>>>(xb, w1b, nullptr, qkv, 4096, 3072, 2048, 0);
    rope_scatter<<<3072, 256, 0, stream>>>(qkv, cosb, sinb, qo, ko, vo);
    vtrans<<<dim3(32, 16), 256, 0, stream>>>(vo, vt);
    attn<<<dim3(16, 32, 2), 256, 0, stream>>>(qo, ko, vt, ao);
    gemm_bt<<<dim3(32, 16), 256, 0, stream>>>(ao, w2b, out, nullptr, 4096, 2048, 2048, 1);
}